// Round 1
// baseline (87.178 us; speedup 1.0000x reference)
//
#include <hip/hip_runtime.h>
#include <cstdint>

// ---------------------------------------------------------------------------
// TileTask_62277025792545: bit-serial int8 conv emulation.
//   conv: 8 bit-planes of cast_in (two's complement), each 3x3x64->64 conv,
//   per-plane q = 2*clip(rne(y/2),-128,127), recombine with [1,2,..,64,-128],
//   +bias, +merge, quant(cmult), +gather, quant(0.75), relu, quant(1), pool2x2.
// Implementation: implicit-GEMM MFMA (bf16), M=(pixel,plane), N=cout, K=ci*9.
// Wave tile: 32 rows = 2x2 pool-quad (4 px) x 8 planes  X  32 cout.
// ---------------------------------------------------------------------------

typedef float   f32x16 __attribute__((ext_vector_type(16)));
typedef __bf16  bf16x8 __attribute__((ext_vector_type(8)));
typedef unsigned int u32x4 __attribute__((ext_vector_type(4)));

#define XB_OFF   0u
#define XB_BYTES 4326400u                      // 4*130*130*64 u8, padded NHWC
#define MG_OFF   (XB_OFF + XB_BYTES)           // merge int8 NHWC
#define MG_BYTES 4194304u                      // 4*128*128*64
#define GT_OFF   (MG_OFF + MG_BYTES)           // gather int8 NHWC
#define WPK_OFF  (GT_OFF + MG_BYTES)           // packed bf16 B-frags
#define WPK_BYTES 73728u                       // 36*2*64*8 ushort
#define OUTN_OFF (WPK_OFF + WPK_BYTES)         // f32 NHWC pooled out

// NCHW f32 (ints in [-128,127]) -> NHWC bytes (two's complement). pad=1 adds
// the conv halo border (dst is 130x130, border pre-zeroed by memset).
__global__ __launch_bounds__(256) void k_to_nhwc(const float* __restrict__ src,
                                                 uint8_t* __restrict__ dst, int pad) {
  const int blk = blockIdx.x, b = blk >> 7, h = blk & 127, t = threadIdx.x;
  __shared__ uint8_t lds[128 * 68];            // [w][ci], +4 pad vs 64 for banks
  const float* s0 = src + ((size_t)(b * 64) * 128 + h) * 128;
#pragma unroll
  for (int ci0 = 0; ci0 < 64; ci0 += 2) {
    const int ci = ci0 + (t >> 7), w = t & 127;
    const float v = s0[ci * 16384 + w];        // coalesced over w
    lds[w * 68 + ci] = (uint8_t)((int)v & 0xFF);
  }
  __syncthreads();
  uint8_t* d0 = dst + (pad ? (((size_t)b * 130 + h + 1) * 130 + 1) * 64
                           : ((size_t)(b * 128 + h) * 128) * 64);
#pragma unroll
  for (int j = 0; j < 8; ++j) {                // 8192B contiguous per (b,h)
    const int f = j * 256 + t;
    const int w = f >> 4, ci4 = f & 15;
    const uint32_t val = *(const uint32_t*)&lds[w * 68 + ci4 * 4];
    *(uint32_t*)(d0 + (size_t)f * 4) = val;
  }
}

// Weight pack: W[co][ci][kh][kw] f32 -> wpk[c][g][lane][8] bf16 in the exact
// B-fragment layout of v_mfma_f32_32x32x16_bf16 (col=lane&31, k=(lane>>5)*8+i),
// with the same within-8 k permutation P=[0,2,1,3,4,6,5,7] the A-build emits.
__global__ __launch_bounds__(256) void k_pack_w(const float* __restrict__ wsrc,
                                                unsigned short* __restrict__ wpk) {
  const int idx = blockIdx.x * 256 + threadIdx.x;   // grid covers exactly 36864
  const int i = idx & 7, l = (idx >> 3) & 63, gg = (idx >> 9) & 1, c = idx >> 10;
  const int pi = (i & 4) | ((i & 1) << 1) | ((i >> 1) & 1);   // P[i]
  const int k = c * 16 + (l >> 5) * 8 + pi;
  const int tap = k >> 6, ci = k & 63;
  const int kh = tap / 3, kw = tap % 3;
  const int cco = gg * 32 + (l & 31);
  const float wv = wsrc[((cco * 64 + ci) * 3 + kh) * 3 + kw];
  wpk[idx] = (unsigned short)(__float_as_uint(wv) >> 16);    // ints: exact bf16
}

__global__ __launch_bounds__(256) void k_main(
    const unsigned char* __restrict__ xb, const signed char* __restrict__ mg,
    const signed char* __restrict__ gt, const unsigned short* __restrict__ wpk,
    const float* __restrict__ bias, const float* __restrict__ cti,
    const float* __restrict__ cts, const float* __restrict__ sti,
    const float* __restrict__ sts, const float* __restrict__ ati,
    const float* __restrict__ ats, float* __restrict__ outn) {
  const int lane = threadIdx.x & 63;
  const int wvid = blockIdx.x * 4 + (threadIdx.x >> 6);
  const int g = wvid & 1;                       // cout half
  const int t2 = wvid >> 1;
  const int wog = t2 & 7;                       // 8 pooled cols per wave
  const int ho = (t2 >> 3) & 63;
  const int b = t2 >> 9;

  // B-fragments held in registers across all 8 quads (essential: /8 L2 traffic)
  u32x4 Bf[36];
#pragma unroll
  for (int c = 0; c < 36; ++c)
    Bf[c] = *(const u32x4*)(wpk + ((size_t)(c * 2 + g) * 64 + lane) * 8);

  const int pix = (lane & 31) >> 3;             // A row = pix*8 + plane
  const int plane = lane & 7;
  const int khalf = lane >> 5;
  const int dh = pix >> 1, dw = pix & 1;
  const int h = ho * 2;
  const unsigned char* xbase =
      xb + ((size_t)((b * 130 + h + dh) * 130) + dw) * 64 + khalf * 8;

  const int co = g * 32 + (lane & 31);
  const float bs = bias[co];
  const float cm = ldexpf(cti[co], (int)cts[co]);   // i * 2^s == i / 2^-s exact
  const float sm = ldexpf(sti[0], (int)sts[0]);
  const float am = ldexpf(ati[0], (int)ats[0]);
  float pwl[4];                                 // this lane's 4 plane weights
  pwl[0] = khalf ? 16.f : 1.f;
  pwl[1] = khalf ? 32.f : 2.f;
  pwl[2] = khalf ? 64.f : 4.f;
  pwl[3] = khalf ? -128.f : 8.f;

  for (int q = 0; q < 8; ++q) {
    const int wo = wog * 8 + q;
    const int w = wo * 2;
    f32x16 acc = {};
#pragma unroll
    for (int c = 0; c < 36; ++c) {              // K = 36 chunks of 16
      const int tap = c >> 2;
      const int kh = tap / 3, kw = tap % 3;     // compile-time after unroll
      const unsigned char* p =
          xbase + ((size_t)(kh * 130 + kw + w)) * 64 + (c & 3) * 16;
      const uint2 vv = *(const uint2*)p;        // 8 ci bytes, L1-resident
      const unsigned t0 = (vv.x >> plane) & 0x01010101u;
      const unsigned t1 = (vv.y >> plane) & 0x01010101u;
      // spread 0/1 bytes to bf16 {0, 1.0}; k-order per 4: [0,2,1,3] (matches B)
      const u32x4 av = {(t0 & 0x00010001u) * 0x3F80u,
                        ((t0 >> 8) & 0x00010001u) * 0x3F80u,
                        (t1 & 0x00010001u) * 0x3F80u,
                        ((t1 >> 8) & 0x00010001u) * 0x3F80u};
      acc = __builtin_amdgcn_mfma_f32_32x32x16_bf16(
          __builtin_bit_cast(bf16x8, av), __builtin_bit_cast(bf16x8, Bf[c]),
          acc, 0, 0, 0);
    }
    // ---- epilogue: reg r -> pixel=r>>2, plane=(r&3)+4*khalf ----
    float psum[4];
#pragma unroll
    for (int px = 0; px < 4; ++px) {
      float s = 0.f;
#pragma unroll
      for (int j = 0; j < 4; ++j) {
        const float y = acc[px * 4 + j];
        const float qq = fminf(fmaxf(rintf(y * 0.5f), -128.f), 127.f);
        s = fmaf(pwl[j], 2.f * qq, s);          // plane_w * 2*clip(rne(y/2))
      }
      psum[px] = s;
    }
#pragma unroll
    for (int px = 0; px < 4; ++px)              // combine plane halves
      psum[px] += __shfl_xor(psum[px], 32);

    float po = -3.0e38f;
#pragma unroll
    for (int px = 0; px < 4; ++px) {
      const int hh = h + (px >> 1), ww = w + (px & 1);
      const size_t moff = ((size_t)((b * 128 + hh) * 128 + ww)) * 64 + co;
      const float x1 = psum[px] + bs + (float)mg[moff];
      const float x2 = fminf(fmaxf(rintf(x1 * cm), -128.f), 127.f);
      const float x3 = x2 + (float)gt[moff];
      const float x4 = fminf(fmaxf(rintf(x3 * sm), -128.f), 127.f);
      const float x5 = fmaxf(x4, 0.f);
      const float x6 = fminf(fmaxf(rintf(x5 * am), -128.f), 127.f);
      po = fmaxf(po, x6);                       // 2x2 maxpool, in-lane
    }
    if (lane < 32)
      outn[((size_t)((b * 64 + ho) * 64 + wo)) * 64 + co] = po;
  }
}

// pooled NHWC f32 -> NCHW f32 output (coalesced both sides via LDS tile)
__global__ __launch_bounds__(256) void k_tr_out(const float* __restrict__ outn,
                                                float* __restrict__ outp) {
  const int blk = blockIdx.x, b = blk >> 6, ho = blk & 63, t = threadIdx.x;
  __shared__ float lds[64 * 65];
  const float* s0 = outn + (size_t)(b * 64 + ho) * 4096;
#pragma unroll
  for (int j = 0; j < 16; ++j) {
    const int f = j * 256 + t, wo = f >> 6, co = f & 63;
    lds[wo * 65 + co] = s0[f];
  }
  __syncthreads();
#pragma unroll
  for (int j = 0; j < 16; ++j) {
    const int f = j * 256 + t, co = f >> 6, wo = f & 63;
    outp[(((size_t)(b * 64 + co)) * 64 + ho) * 64 + wo] = lds[wo * 65 + co];
  }
}

extern "C" void kernel_launch(void* const* d_in, const int* in_sizes, int n_in,
                              void* d_out, int out_size, void* d_ws, size_t ws_size,
                              hipStream_t stream) {
  const float* cast_in = (const float*)d_in[0];
  const float* merge_in = (const float*)d_in[1];
  const float* gather_in = (const float*)d_in[2];
  const float* conv_w = (const float*)d_in[3];
  const float* conv_b = (const float*)d_in[4];
  const float* cti = (const float*)d_in[5];
  const float* cts = (const float*)d_in[6];
  const float* sti = (const float*)d_in[7];
  const float* sts = (const float*)d_in[8];
  const float* ati = (const float*)d_in[9];
  const float* ats = (const float*)d_in[10];

  uint8_t* ws = (uint8_t*)d_ws;
  uint8_t* xb = ws + XB_OFF;
  int8_t* mg = (int8_t*)(ws + MG_OFF);
  int8_t* gt = (int8_t*)(ws + GT_OFF);
  unsigned short* wpk = (unsigned short*)(ws + WPK_OFF);
  float* outn = (float*)(ws + OUTN_OFF);

  hipMemsetAsync(xb, 0, XB_BYTES, stream);      // zero conv halo border
  k_to_nhwc<<<512, 256, 0, stream>>>(cast_in, xb, 1);
  k_to_nhwc<<<512, 256, 0, stream>>>(merge_in, (uint8_t*)mg, 0);
  k_to_nhwc<<<512, 256, 0, stream>>>(gather_in, (uint8_t*)gt, 0);
  k_pack_w<<<144, 256, 0, stream>>>(conv_w, wpk);
  k_main<<<1024, 256, 0, stream>>>(xb, mg, gt, wpk, conv_b, cti, cts, sti, sts,
                                   ati, ats, outn);
  k_tr_out<<<256, 256, 0, stream>>>(outn, (float*)d_out);
}